// Round 21
// baseline (124.760 us; speedup 1.0000x reference)
//
#include <hip/hip_runtime.h>

// VQ codebook: z_e [32,64,64,64] f32 (B,C,W,H), emb [1024,64] f32.
// Outputs: quantized [32,64,64,64] f32, indices [131072] (as f32), vq_loss [1].
//
// R21 = R20 + scan k-split x2 via blockIdx.y (CONSTANT e-traffic, 2x waves):
// each block scans 512 codes for its 128 points; grid (1024,2) -> 8192 waves,
// occupancy 37->~60%. R15's extra-wave failure re-read the full codebook (2x
// traffic); this holds traffic at 1.07GB. Scan emits per-split (m1,m2,k1);
// a finalize kernel merges splits with R20's exact tournament (values
// identical to the sequential scan), writes bestk, appends flagged to list.
// DELTA/rescue/merge/loss = R20 verbatim -> absmax 0.0 by construction.

#define CDIM   64
#define KCODES 1024
#define NPTS   131072
#define WH     4096
#define CWH    262144
#define DELTA  0.008f

typedef __attribute__((ext_vector_type(4))) float f32x4;
typedef __attribute__((ext_vector_type(8))) short bf16x8;
typedef __attribute__((ext_vector_type(8))) unsigned short u16x8;

__device__ inline unsigned short f2bf(float f) {
    unsigned u = __float_as_uint(f);
    return (unsigned short)((u + 0x7FFFu + ((u >> 16) & 1u)) >> 16);
}
__device__ inline float bf2f(unsigned short h) {
    return __uint_as_float(((unsigned)h) << 16);
}

// ---------- prep: E (exact R1 order) + wide swizzle + cnt=0 (R20 verbatim) ----------
__global__ __launch_bounds__(256) void vq_prep(const float* __restrict__ emb,
                                               unsigned short* __restrict__ e_swz,
                                               float* __restrict__ E,
                                               int* __restrict__ cnt) {
    const int id = blockIdx.x * 256 + threadIdx.x;
    if (id == 0) cnt[0] = 0;

    if (id < KCODES) {   // E[c], bit-identical to R1
        const int c = id;
        const float4* e4 = (const float4*)(emb + c * CDIM);
        float s = 0.f;
#pragma unroll
        for (int i = 0; i < CDIM / 4; ++i) {
            float4 v = e4[i];
            s = fmaf(v.x, v.x, s); s = fmaf(v.y, v.y, s);
            s = fmaf(v.z, v.z, s); s = fmaf(v.w, v.w, s);
        }
        E[c] = s;
    }

    if (id < KCODES * 8) {
        const int c  = id >> 3;
        const int kh = (id >> 2) & 1;
        const int g  = id & 3;
        const int ct = c >> 4, col = c & 15;
        const int lane = (g << 4) | col;
        const size_t bh = ((size_t)(ct * 2 + 0) * 2 + kh) * 512 + (size_t)lane * 8;
        const size_t bl = ((size_t)(ct * 2 + 1) * 2 + kh) * 512 + (size_t)lane * 8;
        u16x8 his, los;
#pragma unroll
        for (int j = 0; j < 8; ++j) {
            float v = emb[c * CDIM + kh * 32 + g * 8 + j];
            unsigned short hi = f2bf(v);
            unsigned short lo = f2bf(v - bf2f(hi));
            his[j] = hi;
            los[j] = lo;
        }
        *(u16x8*)&e_swz[bh] = his;
        *(u16x8*)&e_swz[bl] = los;
    }
}

// ---------- MFMA scan: R20 body, k-split via blockIdx.y, cand output ----------
__global__ __launch_bounds__(256) void vq_scan_mfma(const float* __restrict__ z_e,
                                                    const unsigned short* __restrict__ e_swz,
                                                    const float* __restrict__ E,
                                                    float* __restrict__ cm1,
                                                    float* __restrict__ cm2,
                                                    int* __restrict__ ck) {
    const int tid = threadIdx.x;
    const int n0  = blockIdx.x * 128;
    const int ks  = blockIdx.y;          // k-split: codes [ks*512, ks*512+512)
    const int ct0 = ks * 32;             // 32 ct-tiles of 16 codes
    const int b   = n0 >> 12;
    const int wh0 = n0 & 4095;

    __shared__ unsigned short zfrag[8][2][2][512];   // 32 KB

    const float* zp = z_e + (size_t)b * CWH + wh0;
#pragma unroll 4
    for (int i = 0; i < 32; ++i) {
        int flat = i * 256 + tid;
        int c = flat >> 7, p = flat & 127;
        float v = zp[(size_t)c * WH + p];
        unsigned short hi = f2bf(v);
        unsigned short lo = f2bf(v - bf2f(hi));
        int slot = ((((c & 31) >> 3) << 4) | (p & 15)) * 8 + (c & 7);
        zfrag[p >> 4][0][c >> 5][slot] = hi;
        zfrag[p >> 4][1][c >> 5][slot] = lo;
    }
    __syncthreads();

    const int lane = tid & 63;
    const int w    = tid >> 6;

    bf16x8 zf[2][2][2];
#pragma unroll
    for (int pt = 0; pt < 2; ++pt)
#pragma unroll
        for (int s = 0; s < 2; ++s)
#pragma unroll
            for (int kh = 0; kh < 2; ++kh)
                zf[pt][s][kh] = *(const bf16x8*)&zfrag[2 * w + pt][s][kh][lane * 8];

    const bf16x8* ebv = (const bf16x8*)e_swz;
    const int eoff = ((lane >> 4) << 2);

    // 4 independent trackers per point (R20 structure).
    float m1a[4], m2a[4], m1b[4], m2b[4];
    int   k1a[4], k1b[4];
#pragma unroll
    for (int i = 0; i < 4; ++i) {
        m1a[i] = 1e30f; m2a[i] = 1e30f; k1a[i] = 0;
        m1b[i] = 1e30f; m2b[i] = 1e30f; k1b[i] = 0;
    }

    bf16x8 eh0 = ebv[(ct0 * 4 + 0) * 64 + lane];
    bf16x8 eh1 = ebv[(ct0 * 4 + 1) * 64 + lane];
    bf16x8 el0 = ebv[(ct0 * 4 + 2) * 64 + lane];
    bf16x8 el1 = ebv[(ct0 * 4 + 3) * 64 + lane];
    f32x4  Ev  = *(const f32x4*)(E + ct0 * 16 + eoff);

    for (int ctl = 0; ctl < 32; ++ctl) {
        const int ct  = ct0 + ctl;
        const int ctn = ct0 + ((ctl + 1) & 31);
        bf16x8 p0 = ebv[(ctn * 4 + 0) * 64 + lane];
        bf16x8 p1 = ebv[(ctn * 4 + 1) * 64 + lane];
        bf16x8 p2 = ebv[(ctn * 4 + 2) * 64 + lane];
        bf16x8 p3 = ebv[(ctn * 4 + 3) * 64 + lane];
        f32x4  Ep = *(const f32x4*)(E + ctn * 16 + eoff);

        f32x4 acc0 = {0.f, 0.f, 0.f, 0.f};
        f32x4 acc1 = {0.f, 0.f, 0.f, 0.f};
        acc0 = __builtin_amdgcn_mfma_f32_16x16x32_bf16(eh0, zf[0][0][0], acc0, 0, 0, 0);
        acc0 = __builtin_amdgcn_mfma_f32_16x16x32_bf16(eh1, zf[0][0][1], acc0, 0, 0, 0);
        acc0 = __builtin_amdgcn_mfma_f32_16x16x32_bf16(eh0, zf[0][1][0], acc0, 0, 0, 0);
        acc0 = __builtin_amdgcn_mfma_f32_16x16x32_bf16(eh1, zf[0][1][1], acc0, 0, 0, 0);
        acc0 = __builtin_amdgcn_mfma_f32_16x16x32_bf16(el0, zf[0][0][0], acc0, 0, 0, 0);
        acc0 = __builtin_amdgcn_mfma_f32_16x16x32_bf16(el1, zf[0][0][1], acc0, 0, 0, 0);
        acc1 = __builtin_amdgcn_mfma_f32_16x16x32_bf16(eh0, zf[1][0][0], acc1, 0, 0, 0);
        acc1 = __builtin_amdgcn_mfma_f32_16x16x32_bf16(eh1, zf[1][0][1], acc1, 0, 0, 0);
        acc1 = __builtin_amdgcn_mfma_f32_16x16x32_bf16(eh0, zf[1][1][0], acc1, 0, 0, 0);
        acc1 = __builtin_amdgcn_mfma_f32_16x16x32_bf16(eh1, zf[1][1][1], acc1, 0, 0, 0);
        acc1 = __builtin_amdgcn_mfma_f32_16x16x32_bf16(el0, zf[1][0][0], acc1, 0, 0, 0);
        acc1 = __builtin_amdgcn_mfma_f32_16x16x32_bf16(el1, zf[1][0][1], acc1, 0, 0, 0);

        const int kb = ct * 16 + eoff;
#pragma unroll
        for (int i = 0; i < 4; ++i) {
            float s0 = fmaf(-2.0f, acc0[i], Ev[i]);
            if (s0 < m1a[i]) { m2a[i] = m1a[i]; m1a[i] = s0; k1a[i] = kb + i; }
            else             { m2a[i] = fminf(m2a[i], s0); }
            float s1 = fmaf(-2.0f, acc1[i], Ev[i]);
            if (s1 < m1b[i]) { m2b[i] = m1b[i]; m1b[i] = s1; k1b[i] = kb + i; }
            else             { m2b[i] = fminf(m2b[i], s1); }
        }

        eh0 = p0; eh1 = p1; el0 = p2; el1 = p3; Ev = Ep;
    }

    // Merge 4 trackers (R20 tournament), then cross-lane butterfly.
    float m1A = m1a[0], m2A = m2a[0]; int k1A = k1a[0];
    float m1B = m1b[0], m2B = m2b[0]; int k1B = k1b[0];
#pragma unroll
    for (int i = 1; i < 4; ++i) {
        bool take = (m1a[i] < m1A) || (m1a[i] == m1A && k1a[i] < k1A);
        float nm2 = take ? fminf(m1A, m2a[i]) : fminf(m2A, m1a[i]);
        if (take) { m1A = m1a[i]; k1A = k1a[i]; }
        m2A = nm2;
        take = (m1b[i] < m1B) || (m1b[i] == m1B && k1b[i] < k1B);
        nm2 = take ? fminf(m1B, m2b[i]) : fminf(m2B, m1b[i]);
        if (take) { m1B = m1b[i]; k1B = k1b[i]; }
        m2B = nm2;
    }

#pragma unroll
    for (int d = 16; d <= 32; d <<= 1) {
        float om1 = __shfl_xor(m1A, d); int ok1 = __shfl_xor(k1A, d); float om2 = __shfl_xor(m2A, d);
        bool take = (om1 < m1A) || (om1 == m1A && ok1 < k1A);
        float nm2 = take ? fminf(m1A, om2) : fminf(m2A, om1);
        if (take) { m1A = om1; k1A = ok1; }
        m2A = nm2;
        om1 = __shfl_xor(m1B, d); ok1 = __shfl_xor(k1B, d); om2 = __shfl_xor(m2B, d);
        take = (om1 < m1B) || (om1 == m1B && ok1 < k1B);
        nm2 = take ? fminf(m1B, om2) : fminf(m2B, om1);
        if (take) { m1B = om1; k1B = ok1; }
        m2B = nm2;
    }

    if (lane < 16) {
        int na  = n0 + (2 * w + 0) * 16 + lane;
        int nb_ = n0 + (2 * w + 1) * 16 + lane;
        const int base = ks * NPTS;
        cm1[base + na]  = m1A; cm2[base + na]  = m2A; ck[base + na]  = k1A;
        cm1[base + nb_] = m1B; cm2[base + nb_] = m2B; ck[base + nb_] = k1B;
    }
}

// ---------- finalize: merge the 2 k-splits, write bestk, append flagged ----------
__global__ __launch_bounds__(256) void vq_finalize(const float* __restrict__ cm1,
                                                   const float* __restrict__ cm2,
                                                   const int* __restrict__ ck,
                                                   int* __restrict__ bestk,
                                                   int* __restrict__ list,
                                                   int* __restrict__ cnt) {
    const int n = blockIdx.x * 256 + threadIdx.x;
    float a1 = cm1[n],        a2 = cm2[n];        int ak = ck[n];
    float b1 = cm1[NPTS + n], b2 = cm2[NPTS + n]; int bk = ck[NPTS + n];
    // ascending split order + lexicographic (score,k) == global first-min
    bool take = (b1 < a1) || (b1 == a1 && bk < ak);
    float m1 = take ? b1 : a1;
    int   k1 = take ? bk : ak;
    float m2 = take ? fminf(a1, b2) : fminf(a2, b1);
    bestk[n] = k1;
    if (m2 - m1 <= DELTA) { int p = atomicAdd(cnt, 1); list[p] = n; }
}

// ---------- rescue (R20 verbatim): wave-parallel exact f32 rescan ----------
__global__ __launch_bounds__(256) void vq_rescue(const float* __restrict__ z_e,
                                                 const float* __restrict__ emb,
                                                 const float* __restrict__ E,
                                                 const int* __restrict__ list,
                                                 const int* __restrict__ cnt,
                                                 int* __restrict__ bestk) {
    const int total  = cnt[0];
    const int lane   = threadIdx.x & 63;
    const int wid    = (blockIdx.x * 256 + threadIdx.x) >> 6;
    const int nwaves = (gridDim.x * 256) >> 6;

    for (int i = wid; i < total; i += nwaves) {
        const int n  = list[i];
        const int b  = n >> 12, wh = n & 4095;
        const float* zp = z_e + (size_t)b * CWH + wh;
        float z[CDIM];
#pragma unroll
        for (int c = 0; c < CDIM; ++c) z[c] = zp[c * WH];

        float best = 1e30f; int bk = 0;
        const int kbase = lane * 16;
#pragma unroll 4
        for (int j = 0; j < 16; ++j) {
            const int k = kbase + j;
            const float4* er4 = (const float4*)(emb + k * CDIM);
            float d0 = 0.f, d1 = 0.f, d2 = 0.f, d3 = 0.f;
#pragma unroll
            for (int c4 = 0; c4 < CDIM / 4; ++c4) {
                float4 v = er4[c4];
                d0 = fmaf(z[4 * c4 + 0], v.x, d0);
                d1 = fmaf(z[4 * c4 + 1], v.y, d1);
                d2 = fmaf(z[4 * c4 + 2], v.z, d2);
                d3 = fmaf(z[4 * c4 + 3], v.w, d3);
            }
            float dot   = (d0 + d1) + (d2 + d3);
            float score = fmaf(-2.0f, dot, E[k]);
            if (score < best) { best = score; bk = k; }
        }
#pragma unroll
        for (int d = 1; d < 64; d <<= 1) {
            float ob = __shfl_xor(best, d);
            int   ok = __shfl_xor(bk, d);
            if (ob < best || (ob == best && ok < bk)) { best = ob; bk = ok; }
        }
        if (lane == 0) bestk[n] = bk;
    }
}

// ---------- merge (R20 verbatim): vector emb gathers + register transpose ----------
__global__ __launch_bounds__(256) void vq_merge(const float* __restrict__ z_e,
                                                const float* __restrict__ emb,
                                                const int* __restrict__ kf,
                                                float* __restrict__ out_q,
                                                float* __restrict__ out_idx,
                                                float* __restrict__ partials) {
    const int tid = threadIdx.x;
    const int cq  = tid >> 5;
    const int pq  = tid & 31;
    const int n0  = blockIdx.x * 128 + pq * 4;
    const int b   = n0 >> 12;
    const int wh  = n0 & 4095;

    const int4 mk4 = *(const int4*)&kf[n0];
    if (cq == 0) {
        float4 fx = { (float)mk4.x, (float)mk4.y, (float)mk4.z, (float)mk4.w };
        *(float4*)&out_idx[n0] = fx;
    }

    const int c0 = cq * 8;
    float4 e0a = *(const float4*)&emb[mk4.x * CDIM + c0];
    float4 e0b = *(const float4*)&emb[mk4.x * CDIM + c0 + 4];
    float4 e1a = *(const float4*)&emb[mk4.y * CDIM + c0];
    float4 e1b = *(const float4*)&emb[mk4.y * CDIM + c0 + 4];
    float4 e2a = *(const float4*)&emb[mk4.z * CDIM + c0];
    float4 e2b = *(const float4*)&emb[mk4.z * CDIM + c0 + 4];
    float4 e3a = *(const float4*)&emb[mk4.w * CDIM + c0];
    float4 e3b = *(const float4*)&emb[mk4.w * CDIM + c0 + 4];

    float qv[8][4];
    qv[0][0] = e0a.x; qv[0][1] = e1a.x; qv[0][2] = e2a.x; qv[0][3] = e3a.x;
    qv[1][0] = e0a.y; qv[1][1] = e1a.y; qv[1][2] = e2a.y; qv[1][3] = e3a.y;
    qv[2][0] = e0a.z; qv[2][1] = e1a.z; qv[2][2] = e2a.z; qv[2][3] = e3a.z;
    qv[3][0] = e0a.w; qv[3][1] = e1a.w; qv[3][2] = e2a.w; qv[3][3] = e3a.w;
    qv[4][0] = e0b.x; qv[4][1] = e1b.x; qv[4][2] = e2b.x; qv[4][3] = e3b.x;
    qv[5][0] = e0b.y; qv[5][1] = e1b.y; qv[5][2] = e2b.y; qv[5][3] = e3b.y;
    qv[6][0] = e0b.z; qv[6][1] = e1b.z; qv[6][2] = e2b.z; qv[6][3] = e3b.z;
    qv[7][0] = e0b.w; qv[7][1] = e1b.w; qv[7][2] = e2b.w; qv[7][3] = e3b.w;

    const float* zb = z_e   + (size_t)b * CWH + wh;
    float*       qb = out_q + (size_t)b * CWH + wh;
    float lsum = 0.f;
#pragma unroll
    for (int cc = 0; cc < 8; ++cc) {
        const int c = c0 + cc;
        float4 z4 = *(const float4*)&zb[(size_t)c * WH];
        float4 q4 = { qv[cc][0], qv[cc][1], qv[cc][2], qv[cc][3] };
        *(float4*)&qb[(size_t)c * WH] = q4;
        float dx = q4.x - z4.x, dy = q4.y - z4.y;
        float dz = q4.z - z4.z, dw = q4.w - z4.w;
        lsum = fmaf(dx, dx, lsum); lsum = fmaf(dy, dy, lsum);
        lsum = fmaf(dz, dz, lsum); lsum = fmaf(dw, dw, lsum);
    }

    __shared__ float red[256];
    red[tid] = lsum;
    __syncthreads();
    for (int s = 128; s > 0; s >>= 1) {
        if (tid < s) red[tid] += red[tid + s];
        __syncthreads();
    }
    if (tid == 0) partials[blockIdx.x] = red[0];
}

__global__ __launch_bounds__(1024) void vq_loss_fin(const float* __restrict__ partials,
                                                    float* __restrict__ loss) {
    __shared__ float red[1024];
    int t = threadIdx.x;
    red[t] = partials[t];
    __syncthreads();
    for (int s = 512; s > 0; s >>= 1) {
        if (t < s) red[t] += red[t + s];
        __syncthreads();
    }
    if (t == 0) loss[0] = red[0] * (1.25f / 8388608.0f);
}

extern "C" void kernel_launch(void* const* d_in, const int* in_sizes, int n_in,
                              void* d_out, int out_size, void* d_ws, size_t ws_size,
                              hipStream_t stream) {
    const float* z_e = (const float*)d_in[0];
    const float* emb = (const float*)d_in[1];

    float* out      = (float*)d_out;
    float* out_q    = out;
    float* out_idx  = out + 8388608;
    float* out_loss = out + 8388608 + 131072;

    char* w = (char*)d_ws;
    float*          E        = (float*)(w);                      //   4 KB
    unsigned short* e_swz    = (unsigned short*)(w + 4096);      // 256 KB
    int*            bestk    = (int*)(w + 266240);               // 512 KB
    int*            list     = (int*)(w + 790528);               // 512 KB
    float*          cm1      = (float*)(w + 1314816);            //   1 MB [2][NPTS]
    float*          cm2      = (float*)(w + 2363392);            //   1 MB
    int*            ck       = (int*)(w + 3411968);              //   1 MB
    int*            cnt      = (int*)(w + 4460544);              //   4 B
    float*          partials = (float*)(w + 4461568);            //   4 KB

    vq_prep<<<32, 256, 0, stream>>>(emb, e_swz, E, cnt);
    dim3 gscan(NPTS / 128, 2);
    vq_scan_mfma<<<gscan, 256, 0, stream>>>(z_e, e_swz, E, cm1, cm2, ck);
    vq_finalize<<<NPTS / 256, 256, 0, stream>>>(cm1, cm2, ck, bestk, list, cnt);
    vq_rescue<<<2048, 256, 0, stream>>>(z_e, emb, E, list, cnt, bestk);
    vq_merge<<<NPTS / 128, 256, 0, stream>>>(z_e, emb, bestk, out_q, out_idx, partials);
    vq_loss_fin<<<1, 1024, 0, stream>>>(partials, out_loss);
}

// Round 22
// 114.602 us; speedup vs baseline: 1.0886x; 1.0886x over previous
//
#include <hip/hip_runtime.h>

// VQ codebook: z_e [32,64,64,64] f32 (B,C,W,H), emb [1024,64] f32.
// Outputs: quantized [32,64,64,64] f32, indices [131072] (as f32), vq_loss [1].
//
// R22 = R20 verbatim (best: 114.7us). R21's k-split proved the scan is NOT
// TLP-limited (2x blocks at constant traffic -> same 75us) and cost +10us in
// staging/candidate overhead. Ten scan variants all land at 70+-6us; locking
// in the best configuration: R12 pipeline + DELTA 0.008 + compact fused into
// scan + per-slot min-trackers + vectorized merge gathers.

#define CDIM   64
#define KCODES 1024
#define NPTS   131072
#define WH     4096
#define CWH    262144
#define CTILES (KCODES / 16)     // 64
#define DELTA  0.008f

typedef __attribute__((ext_vector_type(4))) float f32x4;
typedef __attribute__((ext_vector_type(8))) short bf16x8;
typedef __attribute__((ext_vector_type(8))) unsigned short u16x8;

__device__ inline unsigned short f2bf(float f) {
    unsigned u = __float_as_uint(f);
    return (unsigned short)((u + 0x7FFFu + ((u >> 16) & 1u)) >> 16);
}
__device__ inline float bf2f(unsigned short h) {
    return __uint_as_float(((unsigned)h) << 16);
}

// ---------- prep: E (exact R1 order) + wide swizzle + cnt=0 ----------
__global__ __launch_bounds__(256) void vq_prep(const float* __restrict__ emb,
                                               unsigned short* __restrict__ e_swz,
                                               float* __restrict__ E,
                                               int* __restrict__ cnt) {
    const int id = blockIdx.x * 256 + threadIdx.x;
    if (id == 0) cnt[0] = 0;

    if (id < KCODES) {   // E[c], bit-identical to R1
        const int c = id;
        const float4* e4 = (const float4*)(emb + c * CDIM);
        float s = 0.f;
#pragma unroll
        for (int i = 0; i < CDIM / 4; ++i) {
            float4 v = e4[i];
            s = fmaf(v.x, v.x, s); s = fmaf(v.y, v.y, s);
            s = fmaf(v.z, v.z, s); s = fmaf(v.w, v.w, s);
        }
        E[c] = s;
    }

    if (id < KCODES * 8) {
        const int c  = id >> 3;
        const int kh = (id >> 2) & 1;
        const int g  = id & 3;
        const int ct = c >> 4, col = c & 15;
        const int lane = (g << 4) | col;
        const size_t bh = ((size_t)(ct * 2 + 0) * 2 + kh) * 512 + (size_t)lane * 8;
        const size_t bl = ((size_t)(ct * 2 + 1) * 2 + kh) * 512 + (size_t)lane * 8;
        u16x8 his, los;
#pragma unroll
        for (int j = 0; j < 8; ++j) {
            float v = emb[c * CDIM + kh * 32 + g * 8 + j];
            unsigned short hi = f2bf(v);
            unsigned short lo = f2bf(v - bf2f(hi));
            his[j] = hi;
            los[j] = lo;
        }
        *(u16x8*)&e_swz[bh] = his;
        *(u16x8*)&e_swz[bl] = los;
    }
}

// ---------- MFMA scan: R12 structure, per-slot independent min-trackers ----------
__global__ __launch_bounds__(256) void vq_scan_mfma(const float* __restrict__ z_e,
                                                    const unsigned short* __restrict__ e_swz,
                                                    const float* __restrict__ E,
                                                    int* __restrict__ bestk,
                                                    int* __restrict__ list,
                                                    int* __restrict__ cnt) {
    const int tid = threadIdx.x;
    const int n0  = blockIdx.x * 128;
    const int b   = n0 >> 12;
    const int wh0 = n0 & 4095;

    __shared__ unsigned short zfrag[8][2][2][512];   // 32 KB

    const float* zp = z_e + (size_t)b * CWH + wh0;
#pragma unroll 4
    for (int i = 0; i < 32; ++i) {
        int flat = i * 256 + tid;
        int c = flat >> 7, p = flat & 127;
        float v = zp[(size_t)c * WH + p];
        unsigned short hi = f2bf(v);
        unsigned short lo = f2bf(v - bf2f(hi));
        int slot = ((((c & 31) >> 3) << 4) | (p & 15)) * 8 + (c & 7);
        zfrag[p >> 4][0][c >> 5][slot] = hi;
        zfrag[p >> 4][1][c >> 5][slot] = lo;
    }
    __syncthreads();

    const int lane = tid & 63;
    const int w    = tid >> 6;

    bf16x8 zf[2][2][2];
#pragma unroll
    for (int pt = 0; pt < 2; ++pt)
#pragma unroll
        for (int s = 0; s < 2; ++s)
#pragma unroll
            for (int kh = 0; kh < 2; ++kh)
                zf[pt][s][kh] = *(const bf16x8*)&zfrag[2 * w + pt][s][kh][lane * 8];

    const bf16x8* ebv = (const bf16x8*)e_swz;
    const int eoff = ((lane >> 4) << 2);

    // 4 independent trackers per point (slot i covers codes ct*16+eoff+i).
    float m1a[4], m2a[4], m1b[4], m2b[4];
    int   k1a[4], k1b[4];
#pragma unroll
    for (int i = 0; i < 4; ++i) {
        m1a[i] = 1e30f; m2a[i] = 1e30f; k1a[i] = 0;
        m1b[i] = 1e30f; m2b[i] = 1e30f; k1b[i] = 0;
    }

    bf16x8 eh0 = ebv[0 * 64 + lane];
    bf16x8 eh1 = ebv[1 * 64 + lane];
    bf16x8 el0 = ebv[2 * 64 + lane];
    bf16x8 el1 = ebv[3 * 64 + lane];
    f32x4  Ev  = *(const f32x4*)(E + eoff);

    for (int ct = 0; ct < CTILES; ++ct) {
        const int ctn = (ct + 1) & 63;
        bf16x8 p0 = ebv[(ctn * 4 + 0) * 64 + lane];
        bf16x8 p1 = ebv[(ctn * 4 + 1) * 64 + lane];
        bf16x8 p2 = ebv[(ctn * 4 + 2) * 64 + lane];
        bf16x8 p3 = ebv[(ctn * 4 + 3) * 64 + lane];
        f32x4  Ep = *(const f32x4*)(E + ctn * 16 + eoff);

        f32x4 acc0 = {0.f, 0.f, 0.f, 0.f};
        f32x4 acc1 = {0.f, 0.f, 0.f, 0.f};
        acc0 = __builtin_amdgcn_mfma_f32_16x16x32_bf16(eh0, zf[0][0][0], acc0, 0, 0, 0);
        acc0 = __builtin_amdgcn_mfma_f32_16x16x32_bf16(eh1, zf[0][0][1], acc0, 0, 0, 0);
        acc0 = __builtin_amdgcn_mfma_f32_16x16x32_bf16(eh0, zf[0][1][0], acc0, 0, 0, 0);
        acc0 = __builtin_amdgcn_mfma_f32_16x16x32_bf16(eh1, zf[0][1][1], acc0, 0, 0, 0);
        acc0 = __builtin_amdgcn_mfma_f32_16x16x32_bf16(el0, zf[0][0][0], acc0, 0, 0, 0);
        acc0 = __builtin_amdgcn_mfma_f32_16x16x32_bf16(el1, zf[0][0][1], acc0, 0, 0, 0);
        acc1 = __builtin_amdgcn_mfma_f32_16x16x32_bf16(eh0, zf[1][0][0], acc1, 0, 0, 0);
        acc1 = __builtin_amdgcn_mfma_f32_16x16x32_bf16(eh1, zf[1][0][1], acc1, 0, 0, 0);
        acc1 = __builtin_amdgcn_mfma_f32_16x16x32_bf16(eh0, zf[1][1][0], acc1, 0, 0, 0);
        acc1 = __builtin_amdgcn_mfma_f32_16x16x32_bf16(eh1, zf[1][1][1], acc1, 0, 0, 0);
        acc1 = __builtin_amdgcn_mfma_f32_16x16x32_bf16(el0, zf[1][0][0], acc1, 0, 0, 0);
        acc1 = __builtin_amdgcn_mfma_f32_16x16x32_bf16(el1, zf[1][0][1], acc1, 0, 0, 0);

        const int kb = ct * 16 + eoff;
#pragma unroll
        for (int i = 0; i < 4; ++i) {
            float s0 = fmaf(-2.0f, acc0[i], Ev[i]);
            if (s0 < m1a[i]) { m2a[i] = m1a[i]; m1a[i] = s0; k1a[i] = kb + i; }
            else             { m2a[i] = fminf(m2a[i], s0); }
            float s1 = fmaf(-2.0f, acc1[i], Ev[i]);
            if (s1 < m1b[i]) { m2b[i] = m1b[i]; m1b[i] = s1; k1b[i] = kb + i; }
            else             { m2b[i] = fminf(m2b[i], s1); }
        }

        eh0 = p0; eh1 = p1; el0 = p2; el1 = p3; Ev = Ep;
    }

    // Merge 4 trackers per point: lexicographic (score, k) tournament.
    float m1A = m1a[0], m2A = m2a[0]; int k1A = k1a[0];
    float m1B = m1b[0], m2B = m2b[0]; int k1B = k1b[0];
#pragma unroll
    for (int i = 1; i < 4; ++i) {
        bool take = (m1a[i] < m1A) || (m1a[i] == m1A && k1a[i] < k1A);
        float nm2 = take ? fminf(m1A, m2a[i]) : fminf(m2A, m1a[i]);
        if (take) { m1A = m1a[i]; k1A = k1a[i]; }
        m2A = nm2;
        take = (m1b[i] < m1B) || (m1b[i] == m1B && k1b[i] < k1B);
        nm2 = take ? fminf(m1B, m2b[i]) : fminf(m2B, m1b[i]);
        if (take) { m1B = m1b[i]; k1B = k1b[i]; }
        m2B = nm2;
    }

#pragma unroll
    for (int d = 16; d <= 32; d <<= 1) {
        float om1 = __shfl_xor(m1A, d); int ok1 = __shfl_xor(k1A, d); float om2 = __shfl_xor(m2A, d);
        bool take = (om1 < m1A) || (om1 == m1A && ok1 < k1A);
        float nm2 = take ? fminf(m1A, om2) : fminf(m2A, om1);
        if (take) { m1A = om1; k1A = ok1; }
        m2A = nm2;
        om1 = __shfl_xor(m1B, d); ok1 = __shfl_xor(k1B, d); om2 = __shfl_xor(m2B, d);
        take = (om1 < m1B) || (om1 == m1B && ok1 < k1B);
        nm2 = take ? fminf(m1B, om2) : fminf(m2B, om1);
        if (take) { m1B = om1; k1B = ok1; }
        m2B = nm2;
    }

    if (lane < 16) {
        int na  = n0 + (2 * w + 0) * 16 + lane;
        int nb_ = n0 + (2 * w + 1) * 16 + lane;
        bestk[na]  = k1A;
        bestk[nb_] = k1B;
        if (m2A - m1A <= DELTA) { int p = atomicAdd(cnt, 1); list[p] = na; }
        if (m2B - m1B <= DELTA) { int p = atomicAdd(cnt, 1); list[p] = nb_; }
    }
}

// ---------- rescue: wave-parallel exact f32 rescan ----------
__global__ __launch_bounds__(256) void vq_rescue(const float* __restrict__ z_e,
                                                 const float* __restrict__ emb,
                                                 const float* __restrict__ E,
                                                 const int* __restrict__ list,
                                                 const int* __restrict__ cnt,
                                                 int* __restrict__ bestk) {
    const int total  = cnt[0];
    const int lane   = threadIdx.x & 63;
    const int wid    = (blockIdx.x * 256 + threadIdx.x) >> 6;
    const int nwaves = (gridDim.x * 256) >> 6;

    for (int i = wid; i < total; i += nwaves) {
        const int n  = list[i];
        const int b  = n >> 12, wh = n & 4095;
        const float* zp = z_e + (size_t)b * CWH + wh;
        float z[CDIM];
#pragma unroll
        for (int c = 0; c < CDIM; ++c) z[c] = zp[c * WH];

        float best = 1e30f; int bk = 0;
        const int kbase = lane * 16;
#pragma unroll 4
        for (int j = 0; j < 16; ++j) {
            const int k = kbase + j;
            const float4* er4 = (const float4*)(emb + k * CDIM);
            float d0 = 0.f, d1 = 0.f, d2 = 0.f, d3 = 0.f;
#pragma unroll
            for (int c4 = 0; c4 < CDIM / 4; ++c4) {
                float4 v = er4[c4];
                d0 = fmaf(z[4 * c4 + 0], v.x, d0);
                d1 = fmaf(z[4 * c4 + 1], v.y, d1);
                d2 = fmaf(z[4 * c4 + 2], v.z, d2);
                d3 = fmaf(z[4 * c4 + 3], v.w, d3);
            }
            float dot   = (d0 + d1) + (d2 + d3);
            float score = fmaf(-2.0f, dot, E[k]);
            if (score < best) { best = score; bk = k; }
        }
#pragma unroll
        for (int d = 1; d < 64; d <<= 1) {
            float ob = __shfl_xor(best, d);
            int   ok = __shfl_xor(bk, d);
            if (ob < best || (ob == best && ok < bk)) { best = ob; bk = ok; }
        }
        if (lane == 0) bestk[n] = bk;
    }
}

// ---------- merge: vector emb gathers + register transpose ----------
__global__ __launch_bounds__(256) void vq_merge(const float* __restrict__ z_e,
                                                const float* __restrict__ emb,
                                                const int* __restrict__ kf,
                                                float* __restrict__ out_q,
                                                float* __restrict__ out_idx,
                                                float* __restrict__ partials) {
    const int tid = threadIdx.x;
    const int cq  = tid >> 5;
    const int pq  = tid & 31;
    const int n0  = blockIdx.x * 128 + pq * 4;
    const int b   = n0 >> 12;
    const int wh  = n0 & 4095;

    const int4 mk4 = *(const int4*)&kf[n0];
    if (cq == 0) {
        float4 fx = { (float)mk4.x, (float)mk4.y, (float)mk4.z, (float)mk4.w };
        *(float4*)&out_idx[n0] = fx;
    }

    const int c0 = cq * 8;
    float4 e0a = *(const float4*)&emb[mk4.x * CDIM + c0];
    float4 e0b = *(const float4*)&emb[mk4.x * CDIM + c0 + 4];
    float4 e1a = *(const float4*)&emb[mk4.y * CDIM + c0];
    float4 e1b = *(const float4*)&emb[mk4.y * CDIM + c0 + 4];
    float4 e2a = *(const float4*)&emb[mk4.z * CDIM + c0];
    float4 e2b = *(const float4*)&emb[mk4.z * CDIM + c0 + 4];
    float4 e3a = *(const float4*)&emb[mk4.w * CDIM + c0];
    float4 e3b = *(const float4*)&emb[mk4.w * CDIM + c0 + 4];

    float qv[8][4];
    qv[0][0] = e0a.x; qv[0][1] = e1a.x; qv[0][2] = e2a.x; qv[0][3] = e3a.x;
    qv[1][0] = e0a.y; qv[1][1] = e1a.y; qv[1][2] = e2a.y; qv[1][3] = e3a.y;
    qv[2][0] = e0a.z; qv[2][1] = e1a.z; qv[2][2] = e2a.z; qv[2][3] = e3a.z;
    qv[3][0] = e0a.w; qv[3][1] = e1a.w; qv[3][2] = e2a.w; qv[3][3] = e3a.w;
    qv[4][0] = e0b.x; qv[4][1] = e1b.x; qv[4][2] = e2b.x; qv[4][3] = e3b.x;
    qv[5][0] = e0b.y; qv[5][1] = e1b.y; qv[5][2] = e2b.y; qv[5][3] = e3b.y;
    qv[6][0] = e0b.z; qv[6][1] = e1b.z; qv[6][2] = e2b.z; qv[6][3] = e3b.z;
    qv[7][0] = e0b.w; qv[7][1] = e1b.w; qv[7][2] = e2b.w; qv[7][3] = e3b.w;

    const float* zb = z_e   + (size_t)b * CWH + wh;
    float*       qb = out_q + (size_t)b * CWH + wh;
    float lsum = 0.f;
#pragma unroll
    for (int cc = 0; cc < 8; ++cc) {
        const int c = c0 + cc;
        float4 z4 = *(const float4*)&zb[(size_t)c * WH];
        float4 q4 = { qv[cc][0], qv[cc][1], qv[cc][2], qv[cc][3] };
        *(float4*)&qb[(size_t)c * WH] = q4;
        float dx = q4.x - z4.x, dy = q4.y - z4.y;
        float dz = q4.z - z4.z, dw = q4.w - z4.w;
        lsum = fmaf(dx, dx, lsum); lsum = fmaf(dy, dy, lsum);
        lsum = fmaf(dz, dz, lsum); lsum = fmaf(dw, dw, lsum);
    }

    __shared__ float red[256];
    red[tid] = lsum;
    __syncthreads();
    for (int s = 128; s > 0; s >>= 1) {
        if (tid < s) red[tid] += red[tid + s];
        __syncthreads();
    }
    if (tid == 0) partials[blockIdx.x] = red[0];
}

__global__ __launch_bounds__(1024) void vq_loss_fin(const float* __restrict__ partials,
                                                    float* __restrict__ loss) {
    __shared__ float red[1024];
    int t = threadIdx.x;
    red[t] = partials[t];
    __syncthreads();
    for (int s = 512; s > 0; s >>= 1) {
        if (t < s) red[t] += red[t + s];
        __syncthreads();
    }
    if (t == 0) loss[0] = red[0] * (1.25f / 8388608.0f);
}

extern "C" void kernel_launch(void* const* d_in, const int* in_sizes, int n_in,
                              void* d_out, int out_size, void* d_ws, size_t ws_size,
                              hipStream_t stream) {
    const float* z_e = (const float*)d_in[0];
    const float* emb = (const float*)d_in[1];

    float* out      = (float*)d_out;
    float* out_q    = out;
    float* out_idx  = out + 8388608;
    float* out_loss = out + 8388608 + 131072;

    char* w = (char*)d_ws;
    float*          E        = (float*)(w);                    //   4 KB
    unsigned short* e_swz    = (unsigned short*)(w + 4096);    // 256 KB
    int*            bestk    = (int*)(w + 266240);             // 512 KB
    int*            list     = (int*)(w + 790528);             // 512 KB
    int*            cnt      = (int*)(w + 1314816);            //   4 B
    float*          partials = (float*)(w + 1315840);          //   4 KB

    vq_prep<<<32, 256, 0, stream>>>(emb, e_swz, E, cnt);
    vq_scan_mfma<<<NPTS / 128, 256, 0, stream>>>(z_e, e_swz, E, bestk, list, cnt);
    vq_rescue<<<2048, 256, 0, stream>>>(z_e, emb, E, list, cnt, bestk);
    vq_merge<<<NPTS / 128, 256, 0, stream>>>(z_e, emb, bestk, out_q, out_idx, partials);
    vq_loss_fin<<<1, 1024, 0, stream>>>(partials, out_loss);
}